// Round 2
// baseline (19556.630 us; speedup 1.0000x reference)
//
#include <hip/hip_runtime.h>
#include <stdint.h>

#define N 8192
#define D 512
#define NEG -1e30f

// ---------------- QKV: Y = X @ W^T (three weight matrices) ----------------
// grid (D/64, N/64, 3), block 256 (tx=t&15 -> d, ty=t>>4 -> n)
// Per thread: 4 n-rows (ty*4+j), 4 d-cols (tx+16*i). No LDS: X row loads are
// 16-lane-uniform (dup-coalesced), W rows stream through L1.
__global__ __launch_bounds__(256) void qkv_gemm(
    const float* __restrict__ X,
    const float* __restrict__ Wq,
    const float* __restrict__ Wk,
    const float* __restrict__ Wv,
    float* __restrict__ ws)
{
    const float* W = (blockIdx.z == 0) ? Wq : (blockIdx.z == 1) ? Wk : Wv;
    float* Y = ws + (size_t)blockIdx.z * ((size_t)N * D);

    const int t  = threadIdx.x;
    const int tx = t & 15;
    const int ty = t >> 4;
    const int d0 = blockIdx.x * 64;
    const int n0 = blockIdx.y * 64;

    const float* xr[4];
    const float* wr[4];
#pragma unroll
    for (int j = 0; j < 4; ++j) xr[j] = X + (size_t)(n0 + ty * 4 + j) * D;
#pragma unroll
    for (int i = 0; i < 4; ++i) wr[i] = W + (size_t)(d0 + tx + 16 * i) * D;

    float acc[4][4] = {};

#pragma unroll 2
    for (int e4 = 0; e4 < D / 4; ++e4) {
        float4 a[4], b[4];
#pragma unroll
        for (int j = 0; j < 4; ++j) a[j] = *(const float4*)(xr[j] + e4 * 4);
#pragma unroll
        for (int i = 0; i < 4; ++i) b[i] = *(const float4*)(wr[i] + e4 * 4);
#pragma unroll
        for (int j = 0; j < 4; ++j) {
#pragma unroll
            for (int i = 0; i < 4; ++i) {
                acc[j][i] += a[j].x * b[i].x + a[j].y * b[i].y +
                             a[j].z * b[i].z + a[j].w * b[i].w;
            }
        }
    }

#pragma unroll
    for (int j = 0; j < 4; ++j) {
#pragma unroll
        for (int i = 0; i < 4; ++i) {
            Y[(size_t)(n0 + ty * 4 + j) * D + d0 + tx + 16 * i] = acc[j][i];
        }
    }
}

// ---------------- masked flash attention ----------------
// grid N/32 = 256 blocks (1 per CU), 512 threads (8 waves).
// thread: tx = t&15, ty = t>>4 (0..31). Each thread owns dst row j = j0+ty,
// score columns i = i0 + tx + 16*ii, and output d-slice d = tx*4 + g*64.
// Row <-> 16 contiguous lanes, so shfl_xor(1,2,4,8) butterflies do row
// max/sum. Only LDS use: P tile (p broadcast across the row's 16 lanes).
__global__ __launch_bounds__(512) void attn_fwd(
    const float* __restrict__ q,
    const float* __restrict__ k,
    const float* __restrict__ v,
    const int* __restrict__ adj,   // jnp bool shipped as int32 (0/1)
    float* __restrict__ out)
{
    __shared__ float Ps[32 * 65];  // [32 rows][64 cols], pad 65 vs bank conflicts

    const int t  = threadIdx.x;
    const int tx = t & 15;
    const int ty = t >> 4;  // 0..31
    const int j0 = blockIdx.x * 32;
    const int j  = j0 + ty;

    const float* qrow = q + (size_t)j * D;

    float acc[8][4] = {};
    float m_run = NEG;
    float l_run = 0.f;

    for (int i0 = 0; i0 < N; i0 += 64) {
        // ---- scores: s[ii] = q_j . k_(i0+tx+16*ii), fp32
        float s[4] = {0.f, 0.f, 0.f, 0.f};
        const float* k0 = k + (size_t)(i0 + tx) * D;
#pragma unroll 4
        for (int e4 = 0; e4 < D / 4; ++e4) {
            float4 a = *(const float4*)(qrow + e4 * 4);
#pragma unroll
            for (int ii = 0; ii < 4; ++ii) {
                float4 b = *(const float4*)(k0 + (size_t)ii * 16 * D + e4 * 4);
                s[ii] += a.x * b.x + a.y * b.y + a.z * b.z + a.w * b.w;
            }
        }

        // ---- mask: score[j,i] valid iff adjacency[i,j] != 0
        bool valid[4];
#pragma unroll
        for (int ii = 0; ii < 4; ++ii) {
            valid[ii] = adj[(size_t)(i0 + tx + 16 * ii) * N + j] != 0;
            if (!valid[ii]) s[ii] = NEG;
        }

        // ---- online softmax update (all 16 lanes of a row agree)
        float mt = fmaxf(fmaxf(s[0], s[1]), fmaxf(s[2], s[3]));
#pragma unroll
        for (int o = 1; o < 16; o <<= 1) mt = fmaxf(mt, __shfl_xor(mt, o, 64));
        float m_new = fmaxf(m_run, mt);

        float p[4];
        float psum = 0.f;
#pragma unroll
        for (int ii = 0; ii < 4; ++ii) {
            p[ii] = valid[ii] ? __expf(s[ii] - m_new) : 0.f;
            psum += p[ii];
        }
#pragma unroll
        for (int o = 1; o < 16; o <<= 1) psum += __shfl_xor(psum, o, 64);

        float scale = __expf(m_run - m_new);  // exp(0)=1 while m_run==m_new==NEG
        l_run = l_run * scale + psum;
        m_run = m_new;
#pragma unroll
        for (int g = 0; g < 8; ++g) {
            acc[g][0] *= scale; acc[g][1] *= scale;
            acc[g][2] *= scale; acc[g][3] *= scale;
        }

        __syncthreads();  // prior i-tile's PV reads of Ps are done
#pragma unroll
        for (int ii = 0; ii < 4; ++ii) Ps[ty * 65 + tx + 16 * ii] = p[ii];
        __syncthreads();  // Ps visible to all row lanes

        // ---- PV: acc[d] += sum_i P[j][i] * v[i][d], double-buffered V rows
        const float* vbase = v + (size_t)i0 * D + tx * 4;
        float4 va[8], vb[8];
#pragma unroll
        for (int g = 0; g < 8; ++g) va[g] = *(const float4*)(vbase + g * 64);

        for (int i = 0; i < 64; i += 2) {
            const float* pvb = vbase + (size_t)(i + 1) * D;
#pragma unroll
            for (int g = 0; g < 8; ++g) vb[g] = *(const float4*)(pvb + g * 64);

            float p0 = Ps[ty * 65 + i];
#pragma unroll
            for (int g = 0; g < 8; ++g) {
                acc[g][0] += p0 * va[g].x; acc[g][1] += p0 * va[g].y;
                acc[g][2] += p0 * va[g].z; acc[g][3] += p0 * va[g].w;
            }

            if (i + 2 < 64) {
                const float* pva = vbase + (size_t)(i + 2) * D;
#pragma unroll
                for (int g = 0; g < 8; ++g) va[g] = *(const float4*)(pva + g * 64);
            }

            float p1 = Ps[ty * 65 + i + 1];
#pragma unroll
            for (int g = 0; g < 8; ++g) {
                acc[g][0] += p1 * vb[g].x; acc[g][1] += p1 * vb[g].y;
                acc[g][2] += p1 * vb[g].z; acc[g][3] += p1 * vb[g].w;
            }
        }
    }

    // ---- epilogue: normalize; rows with no predecessors (l==0) -> 0
    float inv = (l_run > 0.f) ? 1.f / l_run : 0.f;
    float* orow = out + (size_t)j * D + tx * 4;
#pragma unroll
    for (int g = 0; g < 8; ++g) {
        float4 o;
        o.x = acc[g][0] * inv; o.y = acc[g][1] * inv;
        o.z = acc[g][2] * inv; o.w = acc[g][3] * inv;
        *(float4*)(orow + g * 64) = o;
    }
}

extern "C" void kernel_launch(void* const* d_in, const int* in_sizes, int n_in,
                              void* d_out, int out_size, void* d_ws, size_t ws_size,
                              hipStream_t stream) {
    const float* ns  = (const float*)d_in[0];
    const int*   adj = (const int*)d_in[1];   // bool -> int32 per harness
    const float* Wq  = (const float*)d_in[2];
    const float* Wk  = (const float*)d_in[3];
    const float* Wv  = (const float*)d_in[4];

    float* ws  = (float*)d_ws;           // q | k | v, 16 MB each (48 MB total)
    float* out = (float*)d_out;

    dim3 g1(D / 64, N / 64, 3);
    qkv_gemm<<<g1, 256, 0, stream>>>(ns, Wq, Wk, Wv, ws);

    const float* q = ws;
    const float* k = ws + (size_t)N * D;
    const float* v = ws + 2 * (size_t)N * D;
    attn_fwd<<<N / 32, 512, 0, stream>>>(q, k, v, adj, out);
}

// Round 3
// 1456.518 us; speedup vs baseline: 13.4270x; 13.4270x over previous
//
#include <hip/hip_runtime.h>
#include <stdint.h>

#define N 8192
#define D 512
#define NEG -1e30f

typedef _Float16 f16;
typedef f16 f16x8 __attribute__((ext_vector_type(8)));
typedef float f32x4v __attribute__((ext_vector_type(4)));
typedef float f32x16 __attribute__((ext_vector_type(16)));

// ---- workspace layout (bytes) ----
#define QH_OFF 0ull
#define KH_OFF (8192ull * 512 * 2)
#define VT_OFF (2ull * 8192 * 512 * 2)
#define P1_OFF (3ull * 8192 * 512 * 2)              // half-1 partial, fp32, 16 MB
#define ML_OFF (P1_OFF + 8192ull * 512 * 4)         // float2 ml[2][8192]

#define LDSB 116480   // Qs 64K | Ps 16K | Slds 33792 | state 768

// ---------------- QKV: fp32 vector GEMM, fp16 epilogue ----------------
// grid (D/64, N/64, 3), block 256. z=0 -> qh[n][d], z=1 -> kh[n][d], z=2 -> vt[d][n].
__global__ __launch_bounds__(256) void qkv_gemm(
    const float* __restrict__ X,
    const float* __restrict__ Wq,
    const float* __restrict__ Wk,
    const float* __restrict__ Wv,
    f16* __restrict__ qh, f16* __restrict__ kh, f16* __restrict__ vt)
{
    const int z = blockIdx.z;
    const float* W = (z == 0) ? Wq : (z == 1) ? Wk : Wv;

    const int t  = threadIdx.x;
    const int tx = t & 15;
    const int ty = t >> 4;
    const int d0 = blockIdx.x * 64;
    const int n0 = blockIdx.y * 64;

    const float* xr[4];
    const float* wr[4];
#pragma unroll
    for (int j = 0; j < 4; ++j) xr[j] = X + (size_t)(n0 + ty * 4 + j) * D;
#pragma unroll
    for (int i = 0; i < 4; ++i) wr[i] = W + (size_t)(d0 + tx + 16 * i) * D;

    float acc[4][4] = {};

#pragma unroll 2
    for (int e4 = 0; e4 < D / 4; ++e4) {
        float4 a[4], b[4];
#pragma unroll
        for (int j = 0; j < 4; ++j) a[j] = *(const float4*)(xr[j] + e4 * 4);
#pragma unroll
        for (int i = 0; i < 4; ++i) b[i] = *(const float4*)(wr[i] + e4 * 4);
#pragma unroll
        for (int j = 0; j < 4; ++j)
#pragma unroll
            for (int i = 0; i < 4; ++i)
                acc[j][i] += a[j].x * b[i].x + a[j].y * b[i].y +
                             a[j].z * b[i].z + a[j].w * b[i].w;
    }

    if (z == 2) {
#pragma unroll
        for (int j = 0; j < 4; ++j)
#pragma unroll
            for (int i = 0; i < 4; ++i)
                vt[(size_t)(d0 + tx + 16 * i) * N + (n0 + ty * 4 + j)] = (f16)acc[j][i];
    } else {
        f16* Y = z ? kh : qh;
#pragma unroll
        for (int j = 0; j < 4; ++j)
#pragma unroll
            for (int i = 0; i < 4; ++i)
                Y[(size_t)(n0 + ty * 4 + j) * D + d0 + tx + 16 * i] = (f16)acc[j][i];
    }
}

// ---------------- MFMA masked flash attention ----------------
// grid 256: block bx -> j-tile (bx>>1)*64, source half (bx&1)*4096.
// 512 threads = 8 waves: jj = w>>2 (j sub 32), ii = w&3 (i sub 32 of BI=128).
// mfma_f32_32x32x16_f16: A[row=l&31][k=(l>>5)*8+e], B[k=(l>>5)*8+e][col=l&31],
// C row=(r&3)+8*(r>>2)+4*(l>>5), col=l&31.
__global__ __launch_bounds__(512, 2) void attn_mfma(
    const f16* __restrict__ qh, const f16* __restrict__ kh,
    const f16* __restrict__ vt, const int* __restrict__ adj,
    float* __restrict__ p0, float* __restrict__ p1, float2* __restrict__ ml)
{
    extern __shared__ char smem[];
    char*  QsB  = smem;                       // 64 rows x 1024 B, XOR-16B swizzled
    char*  PsB  = smem + 65536;               // 64 rows x 256 B, XOR-16B swizzled
    float* Slds = (float*)(smem + 81920);     // [64][132] fp32
    float* mrow = (float*)(smem + 115712);
    float* lrow = mrow + 64;
    float* scl  = mrow + 128;

    const int t    = threadIdx.x;
    const int w    = t >> 6;
    const int lane = t & 63;
    const int lo   = lane & 31;
    const int hi   = lane >> 5;
    const int jj   = w >> 2;
    const int ii   = w & 3;
    const int jt   = blockIdx.x >> 1;
    const int half = blockIdx.x & 1;
    const int j0   = jt * 64;
    float* pbuf = half ? p1 : p0;

    // ---- stage Q tile into swizzled LDS (once) ----
    {
        const int row = t >> 3;
        const int cb  = t & 7;
#pragma unroll
        for (int c = 0; c < 8; ++c) {
            const int chunk = cb + c * 8;
            f16x8 v = *(const f16x8*)(qh + (size_t)(j0 + row) * D + chunk * 8);
            *(f16x8*)(QsB + ((row * 1024 + chunk * 16) ^ ((row & 7) << 4))) = v;
        }
    }
    if (t < 64) { mrow[t] = NEG; lrow[t] = 0.f; }
    __syncthreads();

    f32x16 oacc[4];
#pragma unroll
    for (int n = 0; n < 4; ++n)
#pragma unroll
        for (int e = 0; e < 16; ++e) oacc[n][e] = 0.f;

    const int qbase = (jj * 32 + lo) * 1024 + hi * 16;
    const int qswz  = (lo & 7) << 4;
    const int pbase = (jj * 32 + lo) * 256 + hi * 16;

    for (int it = 0; it < 32; ++it) {
        const int i0   = half * 4096 + it * 128;
        const int irow = i0 + ii * 32 + lo;

        // mask prefetch: valid(r) = adj[irow][j0 + jj*32 + rmap(r)]
        const int* ab = adj + (size_t)irow * N + j0 + jj * 32 + hi * 4;
        const int4 mm0 = *(const int4*)(ab + 0);
        const int4 mm1 = *(const int4*)(ab + 8);
        const int4 mm2 = *(const int4*)(ab + 16);
        const int4 mm3 = *(const int4*)(ab + 24);

        // ---- QK^T (32 k-steps over D=512) ----
        f32x16 sacc;
#pragma unroll
        for (int e = 0; e < 16; ++e) sacc[e] = 0.f;
        const f16* krow = kh + (size_t)irow * D + hi * 8;
#pragma unroll 4
        for (int ks = 0; ks < 32; ++ks) {
            f16x8 aq = *(const f16x8*)(QsB + ((qbase + ks * 32) ^ qswz));
            f16x8 kb = *(const f16x8*)(krow + ks * 16);
            sacc = __builtin_amdgcn_mfma_f32_32x32x16_f16(aq, kb, sacc, 0, 0, 0);
        }

        // ---- mask + spill S (fp32) to LDS ----
#pragma unroll
        for (int g2 = 0; g2 < 4; ++g2) {
            const int4 mg = (g2 == 0) ? mm0 : (g2 == 1) ? mm1 : (g2 == 2) ? mm2 : mm3;
#pragma unroll
            for (int e = 0; e < 4; ++e) {
                const int valid = (e == 0) ? mg.x : (e == 1) ? mg.y : (e == 2) ? mg.z : mg.w;
                const float s = valid ? sacc[g2 * 4 + e] : NEG;
                Slds[(jj * 32 + e + 8 * g2 + 4 * hi) * 132 + ii * 32 + lo] = s;
            }
        }
        __syncthreads();   // A: S visible

        // ---- softmax phase: thread -> (row = t>>3, seg = t&7), 16 cols each ----
        {
            const int row = t >> 3, seg = t & 7;
            const float* srow = Slds + row * 132 + seg * 16;
            f32x4v sv[4];
#pragma unroll
            for (int k = 0; k < 4; ++k) sv[k] = *(const f32x4v*)(srow + k * 4);
            float mx = NEG;
#pragma unroll
            for (int k = 0; k < 4; ++k)
                mx = fmaxf(mx, fmaxf(fmaxf(sv[k][0], sv[k][1]), fmaxf(sv[k][2], sv[k][3])));
            mx = fmaxf(mx, __shfl_xor(mx, 1, 64));
            mx = fmaxf(mx, __shfl_xor(mx, 2, 64));
            mx = fmaxf(mx, __shfl_xor(mx, 4, 64));
            const float mold = mrow[row];
            const float mnew = fmaxf(mold, mx);
            float ps = 0.f;
            union { f16 h[16]; uint4 u[2]; } pc;
#pragma unroll
            for (int k = 0; k < 4; ++k)
#pragma unroll
                for (int e = 0; e < 4; ++e) {
                    const float sval = sv[k][e];
                    const float pe = (sval > -1e29f) ? __expf(sval - mnew) : 0.f;
                    ps += pe;
                    pc.h[k * 4 + e] = (f16)pe;
                }
            ps += __shfl_xor(ps, 1, 64);
            ps += __shfl_xor(ps, 2, 64);
            ps += __shfl_xor(ps, 4, 64);
            const int pb0 = (row * 256 + seg * 32) ^ ((row & 7) << 4);
            *(uint4*)(PsB + pb0) = pc.u[0];
            *(uint4*)(PsB + (pb0 ^ 16)) = pc.u[1];
            if (seg == 0) {
                const float sc = __expf(mold - mnew);
                lrow[row] = lrow[row] * sc + ps;
                mrow[row] = mnew;
                scl[row]  = sc;
            }
        }
        __syncthreads();   // B: Ps + scale visible

        // ---- rescale + PV ----
        {
            f32x4v scv[4];
#pragma unroll
            for (int g2 = 0; g2 < 4; ++g2)
                scv[g2] = *(const f32x4v*)(scl + jj * 32 + g2 * 8 + hi * 4);
#pragma unroll
            for (int n = 0; n < 4; ++n)
#pragma unroll
                for (int g2 = 0; g2 < 4; ++g2)
#pragma unroll
                    for (int e = 0; e < 4; ++e)
                        oacc[n][g2 * 4 + e] *= scv[g2][e];
        }
        {
            const f16* vbase = vt + i0 + hi * 8;
#pragma unroll 2
            for (int ks2 = 0; ks2 < 8; ++ks2) {
                f16x8 pa = *(const f16x8*)(PsB + ((pbase + ks2 * 32) ^ qswz));
#pragma unroll
                for (int n = 0; n < 4; ++n) {
                    f16x8 vb = *(const f16x8*)(vbase +
                        (size_t)(ii * 128 + n * 32 + lo) * N + ks2 * 16);
                    oacc[n] = __builtin_amdgcn_mfma_f32_32x32x16_f16(pa, vb, oacc[n], 0, 0, 0);
                }
            }
        }
        __syncthreads();   // C: Ps consumed; Slds free for next tile
    }

    // ---- store unnormalized partial + (m, l) ----
#pragma unroll
    for (int n = 0; n < 4; ++n)
#pragma unroll
        for (int r = 0; r < 16; ++r) {
            const int row = j0 + jj * 32 + (r & 3) + 8 * (r >> 2) + 4 * hi;
            pbuf[(size_t)row * D + ii * 128 + n * 32 + lo] = oacc[n][r];
        }
    if (t < 64) {
        float2 v; v.x = mrow[t]; v.y = lrow[t];
        ml[half * N + j0 + t] = v;
    }
}

// ---------------- merge the two source halves ----------------
__global__ __launch_bounds__(256) void merge_halves(
    float* __restrict__ o0, const float* __restrict__ o1,
    const float2* __restrict__ ml)
{
    const int idx = blockIdx.x * 256 + threadIdx.x;   // one float4, 1048576 total
    const int j = idx >> 7;
    const float2 a = ml[j];
    const float2 b = ml[N + j];
    const float m  = fmaxf(a.x, b.x);
    const float e0 = __expf(a.x - m);
    const float e1 = __expf(b.x - m);
    const float L  = a.y * e0 + b.y * e1;
    const float inv = (L > 0.f) ? 1.f / L : 0.f;
    const float4 x0 = ((const float4*)o0)[idx];
    const float4 x1 = ((const float4*)o1)[idx];
    float4 r;
    r.x = (x0.x * e0 + x1.x * e1) * inv;
    r.y = (x0.y * e0 + x1.y * e1) * inv;
    r.z = (x0.z * e0 + x1.z * e1) * inv;
    r.w = (x0.w * e0 + x1.w * e1) * inv;
    ((float4*)o0)[idx] = r;
}

extern "C" void kernel_launch(void* const* d_in, const int* in_sizes, int n_in,
                              void* d_out, int out_size, void* d_ws, size_t ws_size,
                              hipStream_t stream) {
    const float* ns  = (const float*)d_in[0];
    const int*   adj = (const int*)d_in[1];
    const float* Wq  = (const float*)d_in[2];
    const float* Wk  = (const float*)d_in[3];
    const float* Wv  = (const float*)d_in[4];

    char* ws = (char*)d_ws;
    f16*    qh = (f16*)(ws + QH_OFF);
    f16*    kh = (f16*)(ws + KH_OFF);
    f16*    vt = (f16*)(ws + VT_OFF);
    float*  p1 = (float*)(ws + P1_OFF);
    float2* mlb = (float2*)(ws + ML_OFF);
    float*  out = (float*)d_out;

    hipFuncSetAttribute((const void*)attn_mfma,
                        hipFuncAttributeMaxDynamicSharedMemorySize, LDSB);

    qkv_gemm<<<dim3(D / 64, N / 64, 3), 256, 0, stream>>>(ns, Wq, Wk, Wv, qh, kh, vt);
    attn_mfma<<<256, 512, LDSB, stream>>>(qh, kh, vt, adj, out, p1, mlb);
    merge_halves<<<4096, 256, 0, stream>>>(out, p1, mlb);
}

// Round 4
// 619.943 us; speedup vs baseline: 31.5459x; 2.3494x over previous
//
#include <hip/hip_runtime.h>
#include <stdint.h>

#define N 8192
#define D 512
#define NEG -1e30f

typedef _Float16 f16;
typedef f16 f16x4 __attribute__((ext_vector_type(4)));
typedef f16 f16x8 __attribute__((ext_vector_type(8)));
typedef float f32x4v __attribute__((ext_vector_type(4)));
typedef float f32x16 __attribute__((ext_vector_type(16)));

// ---- workspace layout (bytes) ----
#define XH_OFF  0ull
#define WQH_OFF (XH_OFF + 8192ull * 512 * 2)
#define WKH_OFF (WQH_OFF + 512ull * 512 * 2)
#define WVH_OFF (WKH_OFF + 512ull * 512 * 2)
#define QH_OFF  (WVH_OFF + 512ull * 512 * 2)
#define KH_OFF  (QH_OFF + 8192ull * 512 * 2)
#define VT_OFF  (KH_OFF + 8192ull * 512 * 2)
#define P1_OFF  (VT_OFF + 8192ull * 512 * 2)        // half-1 partial, fp32, 16 MB
#define ML_OFF  (P1_OFF + 8192ull * 512 * 4)        // float2 ml[2][8192]

#define LDSB 116480   // Qs 64K | Ps 16K | Slds 33792 | state 768

// ---------------- fp32 -> fp16 conversion (X and the three W's) ----------------
// flat float4 segments: X (1048576) | Wq (65536) | Wk | Wv  => 1245184 float4s
__global__ __launch_bounds__(256) void cvt_fp16(
    const float* __restrict__ X,
    const float* __restrict__ Wq, const float* __restrict__ Wk, const float* __restrict__ Wv,
    f16* __restrict__ Xh,
    f16* __restrict__ Wqh, f16* __restrict__ Wkh, f16* __restrict__ Wvh)
{
    const int idx = blockIdx.x * 256 + threadIdx.x;
    const float* src; f16* dst; int off;
    if (idx < 1048576)      { src = X;  dst = Xh;  off = idx; }
    else if (idx < 1114112) { src = Wq; dst = Wqh; off = idx - 1048576; }
    else if (idx < 1179648) { src = Wk; dst = Wkh; off = idx - 1114112; }
    else                    { src = Wv; dst = Wvh; off = idx - 1179648; }
    const float4 v = ((const float4*)src)[off];
    f16x4 h; h.x = (f16)v.x; h.y = (f16)v.y; h.z = (f16)v.z; h.w = (f16)v.w;
    *(f16x4*)(dst + (size_t)off * 4) = h;
}

// ---------------- QKV via MFMA ----------------
// grid (4, 64, 3), 256 thr = 4 waves, per-wave 32(M) x 128(C) tile, K=512.
// z=0/1: Y[n][d] = sum_e Xh[n][e] W[d][e]   A=Xh rows, B=W rows,  Y=qh/kh [n][d]
// z=2:   vt[d][n] = sum_e Wv[d][e] Xh[n][e] A=Wvh rows, B=Xh rows, Y=vt [d][n]
// All fragment loads are contiguous f16x8 from row-major sources; no LDS.
__global__ __launch_bounds__(256) void qkv_mfma(
    const f16* __restrict__ Xh,
    const f16* __restrict__ Wqh, const f16* __restrict__ Wkh, const f16* __restrict__ Wvh,
    f16* __restrict__ qh, f16* __restrict__ kh, f16* __restrict__ vt)
{
    const int t    = threadIdx.x;
    const int w    = t >> 6;
    const int lane = t & 63;
    const int lo   = lane & 31;
    const int hi   = lane >> 5;
    const int z    = blockIdx.z;

    int m0, c0; const f16 *Ap, *Bp; f16* Yp; size_t ldy;
    if (z == 2) {
        m0 = blockIdx.x * 128 + w * 32; c0 = blockIdx.y * 128;
        Ap = Wvh; Bp = Xh; Yp = vt; ldy = N;
    } else {
        m0 = blockIdx.y * 128 + w * 32; c0 = blockIdx.x * 128;
        Ap = Xh; Bp = z ? Wkh : Wqh; Yp = z ? kh : qh; ldy = D;
    }

    const f16* arow = Ap + (size_t)(m0 + lo) * D + hi * 8;
    const f16* brow[4];
#pragma unroll
    for (int nn = 0; nn < 4; ++nn)
        brow[nn] = Bp + (size_t)(c0 + nn * 32 + lo) * D + hi * 8;

    f32x16 acc[4];
#pragma unroll
    for (int nn = 0; nn < 4; ++nn)
#pragma unroll
        for (int e = 0; e < 16; ++e) acc[nn][e] = 0.f;

#pragma unroll 4
    for (int ks = 0; ks < 32; ++ks) {
        const f16x8 a = *(const f16x8*)(arow + ks * 16);
#pragma unroll
        for (int nn = 0; nn < 4; ++nn) {
            const f16x8 b = *(const f16x8*)(brow[nn] + ks * 16);
            acc[nn] = __builtin_amdgcn_mfma_f32_32x32x16_f16(a, b, acc[nn], 0, 0, 0);
        }
    }

#pragma unroll
    for (int nn = 0; nn < 4; ++nn)
#pragma unroll
        for (int r = 0; r < 16; ++r) {
            const int row = m0 + (r & 3) + 8 * (r >> 2) + 4 * hi;
            Yp[(size_t)row * ldy + c0 + nn * 32 + lo] = (f16)acc[nn][r];
        }
}

// ---------------- MFMA masked flash attention ----------------
// grid 256: block bx -> j-tile (bx>>1)*64, source half (bx&1)*4096.
// 512 threads = 8 waves: jj = w>>2 (j sub 32), ii = w&3 (i sub 32 of BI=128).
__global__ __launch_bounds__(512, 2) void attn_mfma(
    const f16* __restrict__ qh, const f16* __restrict__ kh,
    const f16* __restrict__ vt, const int* __restrict__ adj,
    float* __restrict__ p0, float* __restrict__ p1, float2* __restrict__ ml)
{
    extern __shared__ char smem[];
    char*  QsB  = smem;                       // 64 rows x 1024 B, XOR-16B swizzled
    char*  PsB  = smem + 65536;               // 64 rows x 256 B, XOR-16B swizzled
    float* Slds = (float*)(smem + 81920);     // [64][132] fp32
    float* mrow = (float*)(smem + 115712);
    float* lrow = mrow + 64;
    float* scl  = mrow + 128;

    const int t    = threadIdx.x;
    const int w    = t >> 6;
    const int lane = t & 63;
    const int lo   = lane & 31;
    const int hi   = lane >> 5;
    const int jj   = w >> 2;
    const int ii   = w & 3;
    const int jt   = blockIdx.x >> 1;
    const int half = blockIdx.x & 1;
    const int j0   = jt * 64;
    float* pbuf = half ? p1 : p0;

    // ---- stage Q tile into swizzled LDS (once) ----
    {
        const int row = t >> 3;
        const int cb  = t & 7;
#pragma unroll
        for (int c = 0; c < 8; ++c) {
            const int chunk = cb + c * 8;
            f16x8 v = *(const f16x8*)(qh + (size_t)(j0 + row) * D + chunk * 8);
            *(f16x8*)(QsB + ((row * 1024 + chunk * 16) ^ ((row & 7) << 4))) = v;
        }
    }
    if (t < 64) { mrow[t] = NEG; lrow[t] = 0.f; }
    __syncthreads();

    f32x16 oacc[4];
#pragma unroll
    for (int n = 0; n < 4; ++n)
#pragma unroll
        for (int e = 0; e < 16; ++e) oacc[n][e] = 0.f;

    const int qbase = (jj * 32 + lo) * 1024 + hi * 16;
    const int qswz  = (lo & 7) << 4;
    const int pbase = (jj * 32 + lo) * 256 + hi * 16;

    for (int it = 0; it < 32; ++it) {
        const int i0   = half * 4096 + it * 128;
        const int irow = i0 + ii * 32 + lo;

        // mask prefetch: valid(r) = adj[irow][j0 + jj*32 + rmap(r)]
        const int* ab = adj + (size_t)irow * N + j0 + jj * 32 + hi * 4;
        const int4 mm0 = *(const int4*)(ab + 0);
        const int4 mm1 = *(const int4*)(ab + 8);
        const int4 mm2 = *(const int4*)(ab + 16);
        const int4 mm3 = *(const int4*)(ab + 24);

        // ---- QK^T (32 k-steps over D=512) ----
        f32x16 sacc;
#pragma unroll
        for (int e = 0; e < 16; ++e) sacc[e] = 0.f;
        const f16* krow = kh + (size_t)irow * D + hi * 8;
#pragma unroll 4
        for (int ks = 0; ks < 32; ++ks) {
            f16x8 aq = *(const f16x8*)(QsB + ((qbase + ks * 32) ^ qswz));
            f16x8 kb = *(const f16x8*)(krow + ks * 16);
            sacc = __builtin_amdgcn_mfma_f32_32x32x16_f16(aq, kb, sacc, 0, 0, 0);
        }

        // ---- mask + spill S (fp32) to LDS ----
#pragma unroll
        for (int g2 = 0; g2 < 4; ++g2) {
            const int4 mg = (g2 == 0) ? mm0 : (g2 == 1) ? mm1 : (g2 == 2) ? mm2 : mm3;
#pragma unroll
            for (int e = 0; e < 4; ++e) {
                const int valid = (e == 0) ? mg.x : (e == 1) ? mg.y : (e == 2) ? mg.z : mg.w;
                const float s = valid ? sacc[g2 * 4 + e] : NEG;
                Slds[(jj * 32 + e + 8 * g2 + 4 * hi) * 132 + ii * 32 + lo] = s;
            }
        }
        __syncthreads();   // A: S visible

        // ---- softmax phase: thread -> (row = t>>3, seg = t&7), 16 cols each ----
        {
            const int row = t >> 3, seg = t & 7;
            const float* srow = Slds + row * 132 + seg * 16;
            f32x4v sv[4];
#pragma unroll
            for (int k = 0; k < 4; ++k) sv[k] = *(const f32x4v*)(srow + k * 4);
            float mx = NEG;
#pragma unroll
            for (int k = 0; k < 4; ++k)
                mx = fmaxf(mx, fmaxf(fmaxf(sv[k][0], sv[k][1]), fmaxf(sv[k][2], sv[k][3])));
            mx = fmaxf(mx, __shfl_xor(mx, 1, 64));
            mx = fmaxf(mx, __shfl_xor(mx, 2, 64));
            mx = fmaxf(mx, __shfl_xor(mx, 4, 64));
            const float mold = mrow[row];
            const float mnew = fmaxf(mold, mx);
            float ps = 0.f;
            union { f16 h[16]; uint4 u[2]; } pc;
#pragma unroll
            for (int k = 0; k < 4; ++k)
#pragma unroll
                for (int e = 0; e < 4; ++e) {
                    const float sval = sv[k][e];
                    const float pe = (sval > -1e29f) ? __expf(sval - mnew) : 0.f;
                    ps += pe;
                    pc.h[k * 4 + e] = (f16)pe;
                }
            ps += __shfl_xor(ps, 1, 64);
            ps += __shfl_xor(ps, 2, 64);
            ps += __shfl_xor(ps, 4, 64);
            const int pb0 = (row * 256 + seg * 32) ^ ((row & 7) << 4);
            *(uint4*)(PsB + pb0) = pc.u[0];
            *(uint4*)(PsB + (pb0 ^ 16)) = pc.u[1];
            if (seg == 0) {
                const float sc = __expf(mold - mnew);
                lrow[row] = lrow[row] * sc + ps;
                mrow[row] = mnew;
                scl[row]  = sc;
            }
        }
        __syncthreads();   // B: Ps + scale visible

        // ---- rescale + PV ----
        {
            f32x4v scv[4];
#pragma unroll
            for (int g2 = 0; g2 < 4; ++g2)
                scv[g2] = *(const f32x4v*)(scl + jj * 32 + g2 * 8 + hi * 4);
#pragma unroll
            for (int n = 0; n < 4; ++n)
#pragma unroll
                for (int g2 = 0; g2 < 4; ++g2)
#pragma unroll
                    for (int e = 0; e < 4; ++e)
                        oacc[n][g2 * 4 + e] *= scv[g2][e];
        }
        {
            const f16* vbase = vt + i0 + hi * 8;
#pragma unroll 2
            for (int ks2 = 0; ks2 < 8; ++ks2) {
                f16x8 pa = *(const f16x8*)(PsB + ((pbase + ks2 * 32) ^ qswz));
#pragma unroll
                for (int n = 0; n < 4; ++n) {
                    f16x8 vb = *(const f16x8*)(vbase +
                        (size_t)(ii * 128 + n * 32 + lo) * N + ks2 * 16);
                    oacc[n] = __builtin_amdgcn_mfma_f32_32x32x16_f16(pa, vb, oacc[n], 0, 0, 0);
                }
            }
        }
        __syncthreads();   // C: Ps consumed; Slds free for next tile
    }

    // ---- store unnormalized partial + (m, l) ----
#pragma unroll
    for (int n = 0; n < 4; ++n)
#pragma unroll
        for (int r = 0; r < 16; ++r) {
            const int row = j0 + jj * 32 + (r & 3) + 8 * (r >> 2) + 4 * hi;
            pbuf[(size_t)row * D + ii * 128 + n * 32 + lo] = oacc[n][r];
        }
    if (t < 64) {
        float2 v; v.x = mrow[t]; v.y = lrow[t];
        ml[half * N + j0 + t] = v;
    }
}

// ---------------- merge the two source halves ----------------
__global__ __launch_bounds__(256) void merge_halves(
    float* __restrict__ o0, const float* __restrict__ o1,
    const float2* __restrict__ ml)
{
    const int idx = blockIdx.x * 256 + threadIdx.x;   // one float4, 1048576 total
    const int j = idx >> 7;
    const float2 a = ml[j];
    const float2 b = ml[N + j];
    const float m  = fmaxf(a.x, b.x);
    const float e0 = __expf(a.x - m);
    const float e1 = __expf(b.x - m);
    const float L  = a.y * e0 + b.y * e1;
    const float inv = (L > 0.f) ? 1.f / L : 0.f;
    const float4 x0 = ((const float4*)o0)[idx];
    const float4 x1 = ((const float4*)o1)[idx];
    float4 r;
    r.x = (x0.x * e0 + x1.x * e1) * inv;
    r.y = (x0.y * e0 + x1.y * e1) * inv;
    r.z = (x0.z * e0 + x1.z * e1) * inv;
    r.w = (x0.w * e0 + x1.w * e1) * inv;
    ((float4*)o0)[idx] = r;
}

extern "C" void kernel_launch(void* const* d_in, const int* in_sizes, int n_in,
                              void* d_out, int out_size, void* d_ws, size_t ws_size,
                              hipStream_t stream) {
    const float* ns  = (const float*)d_in[0];
    const int*   adj = (const int*)d_in[1];
    const float* Wq  = (const float*)d_in[2];
    const float* Wk  = (const float*)d_in[3];
    const float* Wv  = (const float*)d_in[4];

    char* ws = (char*)d_ws;
    f16*    Xh  = (f16*)(ws + XH_OFF);
    f16*    Wqh = (f16*)(ws + WQH_OFF);
    f16*    Wkh = (f16*)(ws + WKH_OFF);
    f16*    Wvh = (f16*)(ws + WVH_OFF);
    f16*    qh  = (f16*)(ws + QH_OFF);
    f16*    kh  = (f16*)(ws + KH_OFF);
    f16*    vt  = (f16*)(ws + VT_OFF);
    float*  p1  = (float*)(ws + P1_OFF);
    float2* mlb = (float2*)(ws + ML_OFF);
    float*  out = (float*)d_out;

    hipFuncSetAttribute((const void*)attn_mfma,
                        hipFuncAttributeMaxDynamicSharedMemorySize, LDSB);

    cvt_fp16<<<4864, 256, 0, stream>>>(ns, Wq, Wk, Wv, Xh, Wqh, Wkh, Wvh);
    qkv_mfma<<<dim3(4, 64, 3), 256, 0, stream>>>(Xh, Wqh, Wkh, Wvh, qh, kh, vt);
    attn_mfma<<<256, 512, LDSB, stream>>>(qh, kh, vt, adj, out, p1, mlb);
    merge_halves<<<4096, 256, 0, stream>>>(out, p1, mlb);
}